// Round 6
// baseline (152.070 us; speedup 1.0000x reference)
//
#include <hip/hip_runtime.h>
#include <cmath>

#define FIN 256
#define FQK 256
#define SCALING 0.0625f  // FQK^-0.5 = 1/16
#define MAX_SEG 256

typedef __bf16 bf16_t;
typedef bf16_t bf16x8 __attribute__((ext_vector_type(8)));
typedef float  f32x4  __attribute__((ext_vector_type(4)));

__device__ __forceinline__ unsigned short f2bf(float f) {
    unsigned int u = __float_as_uint(f);
    u += 0x7FFFu + ((u >> 16) & 1u);   // RNE
    return (unsigned short)(u >> 16);
}
__device__ __forceinline__ float bf_lo(unsigned int w) { return __uint_as_float(w << 16); }
__device__ __forceinline__ float bf_hi(unsigned int w) { return __uint_as_float(w & 0xFFFF0000u); }

// ---------------------------------------------------------------------------
// Kernel 1: qk projection, B direct from W (native [f][c] layout = contiguous k).
//   h = blockIdx.y: 0 -> q[n][f] = SCALING * sum_c x[n][c]*W[f][c]
//                   1 -> k[n][f] =           sum_c x[n][c]*W[256+f][c]
// 32-row tile per block, 4 waves; wave wv owns f-slice wv*64..+64.
// bf16 MFMA 16x16x32; A (x) staged fp32->bf16 via LDS; B converted on the fly.
// ---------------------------------------------------------------------------
#define ASTRIDE 40
#define GROWS   32

__global__ __launch_bounds__(256) void gemm_qk_kernel(const float* __restrict__ x,
                                                      const float* __restrict__ W,
                                                      unsigned short* __restrict__ qarr,
                                                      unsigned short* __restrict__ karr,
                                                      int N) {
    __shared__ unsigned short sA[GROWS * ASTRIDE];

    const int h    = blockIdx.y;
    const float* __restrict__ Wh = W + (size_t)h * FQK * FIN;
    unsigned short* __restrict__ outp = h ? karr : qarr;
    const float scale = h ? 1.0f : SCALING;

    const int t    = threadIdx.x;
    const int wv   = t >> 6;
    const int lane = t & 63;
    const int q    = lane >> 4;
    const int m16  = lane & 15;
    const int n0   = blockIdx.x * GROWS;
    const int f0   = wv * 64;

    f32x4 acc[2][4] = {};

    const int srow = t >> 3;
    const int skc  = (t & 7) * 4;

    for (int kc = 0; kc < FIN; kc += 32) {
        {
            const int n = n0 + srow;
            float4 v = make_float4(0.f, 0.f, 0.f, 0.f);
            if (n < N) v = *(const float4*)(x + (size_t)n * FIN + kc + skc);
            unsigned short* p = &sA[srow * ASTRIDE + skc];
            p[0] = f2bf(v.x); p[1] = f2bf(v.y); p[2] = f2bf(v.z); p[3] = f2bf(v.w);
        }
        __syncthreads();

        bf16x8 afrag[2];
#pragma unroll
        for (int mt = 0; mt < 2; ++mt)
            afrag[mt] = *(const bf16x8*)&sA[(mt * 16 + m16) * ASTRIDE + q * 8];
#pragma unroll
        for (int ft = 0; ft < 4; ++ft) {
            const int f = f0 + ft * 16 + m16;
            // B'[k][n]: 8 consecutive c-values of W[f] -> fp32 loads, cvt bf16
            const float4 b0 = *(const float4*)(Wh + (size_t)f * FIN + kc + q * 8);
            const float4 b1 = *(const float4*)(Wh + (size_t)f * FIN + kc + q * 8 + 4);
            union { unsigned short s[8]; bf16x8 v; } bu;
            bu.s[0] = f2bf(b0.x); bu.s[1] = f2bf(b0.y); bu.s[2] = f2bf(b0.z); bu.s[3] = f2bf(b0.w);
            bu.s[4] = f2bf(b1.x); bu.s[5] = f2bf(b1.y); bu.s[6] = f2bf(b1.z); bu.s[7] = f2bf(b1.w);
#pragma unroll
            for (int mt = 0; mt < 2; ++mt)
                acc[mt][ft] = __builtin_amdgcn_mfma_f32_16x16x32_bf16(afrag[mt], bu.v,
                                                                     acc[mt][ft], 0, 0, 0);
        }
        __syncthreads();
    }

    // store: within 16x16 tile, col = m16 (f), row = q*4 + r (n)
#pragma unroll
    for (int mt = 0; mt < 2; ++mt) {
#pragma unroll
        for (int r = 0; r < 4; ++r) {
            const int n = n0 + mt * 16 + q * 4 + r;
            if (n < N) {
#pragma unroll
                for (int ft = 0; ft < 4; ++ft)
                    outp[(size_t)n * FIN + f0 + ft * 16 + m16] = f2bf(acc[mt][ft][r] * scale);
            }
        }
    }
}

// ---------------------------------------------------------------------------
// Kernel 2: seg[n] = lower_bound(src, n)  (separate: 20K-way parallel; fusing
// it into node_edge regressed in R4)
// ---------------------------------------------------------------------------
__global__ __launch_bounds__(256) void seg_kernel(const int* __restrict__ src,
                                                  int* __restrict__ seg, int N, int E) {
    const int n = blockIdx.x * 256 + threadIdx.x;
    if (n > N) return;
    int lo = 0, hi = E;
    while (lo < hi) {
        const int mid = (lo + hi) >> 1;
        if (src[mid] < n) lo = mid + 1; else hi = mid;
    }
    seg[n] = lo;
}

// ---------------------------------------------------------------------------
// Kernel 3: one wave per node; q[s] bf16 in regs, k[d] bf16 gathered.
// 4 slots x 16 sublanes; x2 unroll -> 4 outstanding uint4 loads/lane;
// 256 B contiguous per 16-lane slot-group per load instruction.
// ---------------------------------------------------------------------------
__global__ __launch_bounds__(256) void node_edge_kernel(const unsigned short* __restrict__ qarr,
                                                        const unsigned short* __restrict__ karr,
                                                        const int* __restrict__ dest,
                                                        const int* __restrict__ seg,
                                                        float* __restrict__ out, int N) {
    __shared__ float exlds[4][MAX_SEG];

    const int w    = threadIdx.x >> 6;
    const int lane = threadIdx.x & 63;
    const int n    = blockIdx.x * 4 + w;
    const int g    = lane >> 4;   // slot 0..3
    const int j    = lane & 15;   // sublane 0..15

    int   s0 = 0, cnt = 0;
    float inv = 0.f;

    if (n < N) {
        s0 = seg[n];
        cnt = seg[n + 1] - s0;
    }

    if (cnt > 0) {
        // q[n] slices matching the k-load pattern: uint4 idx j and 16+j
        const uint4* __restrict__ qr = (const uint4*)(qarr + (size_t)n * FIN);
        const uint4 qa0 = qr[j];
        const uint4 qa1 = qr[16 + j];
        float4 xa, xb, xc, xd;
        xa.x = bf_lo(qa0.x); xa.y = bf_hi(qa0.x); xa.z = bf_lo(qa0.y); xa.w = bf_hi(qa0.y);
        xb.x = bf_lo(qa0.z); xb.y = bf_hi(qa0.z); xb.z = bf_lo(qa0.w); xb.w = bf_hi(qa0.w);
        xc.x = bf_lo(qa1.x); xc.y = bf_hi(qa1.x); xc.z = bf_lo(qa1.y); xc.w = bf_hi(qa1.y);
        xd.x = bf_lo(qa1.z); xd.y = bf_hi(qa1.z); xd.z = bf_lo(qa1.w); xd.w = bf_hi(qa1.w);

        float sum = 0.f;
        for (int base = 0; base < cnt; base += 64) {
            const int m = min(64, cnt - base);
            const int vd = (lane < m) ? dest[s0 + base + lane] : 0;
            const int nit = (m + 3) >> 2;
            for (int it = 0; it < nit; it += 2) {
                const int  eg0 = it * 4 + g;
                const int  eg1 = eg0 + 4;
                const bool v0  = eg0 < m;
                const bool v1  = eg1 < m;
                const int  d0  = __shfl(vd, eg0, 64);
                const int  d1  = __shfl(vd, eg1, 64);
                const uint4* __restrict__ kr0 = (const uint4*)(karr + (size_t)(v0 ? d0 : 0) * FIN);
                const uint4* __restrict__ kr1 = (const uint4*)(karr + (size_t)(v1 ? d1 : 0) * FIN);
                const uint4 q00 = kr0[j];
                const uint4 q01 = kr0[16 + j];
                const uint4 q10 = kr1[j];
                const uint4 q11 = kr1[16 + j];

                float a0 = 0.f, a1 = 0.f;
                a0 += bf_lo(q00.x) * xa.x + bf_hi(q00.x) * xa.y
                    + bf_lo(q00.y) * xa.z + bf_hi(q00.y) * xa.w
                    + bf_lo(q00.z) * xb.x + bf_hi(q00.z) * xb.y
                    + bf_lo(q00.w) * xb.z + bf_hi(q00.w) * xb.w;
                a0 += bf_lo(q01.x) * xc.x + bf_hi(q01.x) * xc.y
                    + bf_lo(q01.y) * xc.z + bf_hi(q01.y) * xc.w
                    + bf_lo(q01.z) * xd.x + bf_hi(q01.z) * xd.y
                    + bf_lo(q01.w) * xd.z + bf_hi(q01.w) * xd.w;
                a1 += bf_lo(q10.x) * xa.x + bf_hi(q10.x) * xa.y
                    + bf_lo(q10.y) * xa.z + bf_hi(q10.y) * xa.w
                    + bf_lo(q10.z) * xb.x + bf_hi(q10.z) * xb.y
                    + bf_lo(q10.w) * xb.z + bf_hi(q10.w) * xb.w;
                a1 += bf_lo(q11.x) * xc.x + bf_hi(q11.x) * xc.y
                    + bf_lo(q11.y) * xc.z + bf_hi(q11.y) * xc.w
                    + bf_lo(q11.z) * xd.x + bf_hi(q11.z) * xd.y
                    + bf_lo(q11.w) * xd.z + bf_hi(q11.w) * xd.w;

                a0 += __shfl_xor(a0, 1, 64);
                a1 += __shfl_xor(a1, 1, 64);
                a0 += __shfl_xor(a0, 2, 64);
                a1 += __shfl_xor(a1, 2, 64);
                a0 += __shfl_xor(a0, 4, 64);
                a1 += __shfl_xor(a1, 4, 64);
                a0 += __shfl_xor(a0, 8, 64);
                a1 += __shfl_xor(a1, 8, 64);

                if (v0) {
                    const float ex = __expf(a0);
                    sum += ex;
                    const int idx = base + eg0;
                    if (j == 0 && idx < MAX_SEG) exlds[w][idx] = ex;
                }
                if (v1) {
                    const float ex = __expf(a1);
                    sum += ex;
                    const int idx = base + eg1;
                    if (j == 0 && idx < MAX_SEG) exlds[w][idx] = ex;
                }
            }
        }
        sum += __shfl_xor(sum, 16, 64);
        sum += __shfl_xor(sum, 32, 64);
        inv = 1.0f / sum;
    }

    __syncthreads();

    if (cnt > 0) {
        const int lim = cnt < MAX_SEG ? cnt : MAX_SEG;
        for (int i = lane; i < lim; i += 64)
            out[s0 + i] = exlds[w][i] * inv;
    }
}

// ---------------------------------------------------------------------------
extern "C" void kernel_launch(void* const* d_in, const int* in_sizes, int n_in,
                              void* d_out, int out_size, void* d_ws, size_t ws_size,
                              hipStream_t stream) {
    const float* x  = (const float*)d_in[0];
    const int*   ei = (const int*)d_in[1];   // src = ei[0:E], dest = ei[E:2E]
    const float* W  = (const float*)d_in[2];
    float* out = (float*)d_out;

    const int N = in_sizes[0] / FIN;
    const int E = in_sizes[1] / 2;

    // workspace layout
    unsigned short* qarr = (unsigned short*)d_ws;          // N*256 bf16
    unsigned short* karr = qarr + (size_t)N * FIN;         // N*256 bf16
    int*            seg  = (int*)(karr + (size_t)N * FIN); // N+1

    dim3 ggrid((N + GROWS - 1) / GROWS, 2);
    gemm_qk_kernel<<<ggrid, 256, 0, stream>>>(x, W, qarr, karr, N);

    seg_kernel<<<(N + 256) / 256, 256, 0, stream>>>(ei, seg, N, E);

    node_edge_kernel<<<(N + 3) / 4, 256, 0, stream>>>(qarr, karr, ei + E, seg, out, N);
}

// Round 7
// 140.573 us; speedup vs baseline: 1.0818x; 1.0818x over previous
//
#include <hip/hip_runtime.h>
#include <cmath>

#define FIN 256
#define FQK 256
#define SCALING 0.0625f  // FQK^-0.5 = 1/16
#define MAX_SEG 256

typedef __bf16 bf16_t;
typedef bf16_t bf16x8 __attribute__((ext_vector_type(8)));
typedef float  f32x4  __attribute__((ext_vector_type(4)));

__device__ __forceinline__ unsigned short f2bf(float f) {
    unsigned int u = __float_as_uint(f);
    u += 0x7FFFu + ((u >> 16) & 1u);   // RNE
    return (unsigned short)(u >> 16);
}
__device__ __forceinline__ float bf_lo(unsigned int w) { return __uint_as_float(w << 16); }
__device__ __forceinline__ float bf_hi(unsigned int w) { return __uint_as_float(w & 0xFFFF0000u); }
__device__ __forceinline__ unsigned int pack2(float a, float b) {
    return (unsigned int)f2bf(a) | ((unsigned int)f2bf(b) << 16);
}

// ---------------------------------------------------------------------------
// Kernel 0: Wb = bf16(W)  (512x256; makes GEMM B-frags single uint4 loads)
// ---------------------------------------------------------------------------
__global__ __launch_bounds__(256) void prep_wb_kernel(const float* __restrict__ W,
                                                      unsigned int* __restrict__ Wb2) {
    const int i = blockIdx.x * 256 + threadIdx.x;   // uint2 index (4 elems)
    const float4 v = *(const float4*)(W + (size_t)i * 4);
    uint2 p;
    p.x = pack2(v.x, v.y);
    p.y = pack2(v.z, v.w);
    *(uint2*)(Wb2 + (size_t)i * 2) = p;
}

// ---------------------------------------------------------------------------
// Kernel 1: qk projection. h=blockIdx.y: 0->q (scaled), 1->k.
// 32 rows/block, 4 waves, wave wv owns f-slice wv*64..+64.
// Structure: full A-tile staged once (LDS), all 32 B-frags prefetched to
// VGPRs from L2-resident Wb, ONE barrier, then pure ds_read+MFMA.
// ---------------------------------------------------------------------------
#define GROWS    32
#define SAROW    264   // shorts per LDS row (528 B; conflict-free b128 pattern)

__global__ __launch_bounds__(256) void gemm_qk_kernel(const float* __restrict__ x,
                                                      const unsigned short* __restrict__ Wb,
                                                      unsigned short* __restrict__ qarr,
                                                      unsigned short* __restrict__ karr,
                                                      int N) {
    __shared__ unsigned short sA[GROWS * SAROW];

    const int h    = blockIdx.y;
    const unsigned short* __restrict__ Wbh = Wb + (size_t)h * FQK * FIN;
    unsigned short* __restrict__ outp = h ? karr : qarr;
    const float scale = h ? 1.0f : SCALING;

    const int t    = threadIdx.x;
    const int wv   = t >> 6;
    const int lane = t & 63;
    const int q    = lane >> 4;
    const int m16  = lane & 15;
    const int n0   = blockIdx.x * GROWS;
    const int f0   = wv * 64;

    // ---- B prefetch: 32 independent uint4 loads (all of this wave's 64x256
    // bf16 B-slice), issued before the barrier; L2-resident (Wb = 256 KB).
    uint4 bfrag[4][8];
#pragma unroll
    for (int ft = 0; ft < 4; ++ft) {
        const unsigned short* __restrict__ brow = Wbh + (size_t)(f0 + ft * 16 + m16) * FIN;
#pragma unroll
        for (int kc = 0; kc < 8; ++kc)
            bfrag[ft][kc] = *(const uint4*)(brow + kc * 32 + q * 8);
    }

    // ---- A stage: full 32x256 tile, fp32->bf16, 8 float4 loads/thread.
    {
        const int r  = t >> 6;          // 0..3
        const int c4 = (t & 63) * 4;    // col (floats == shorts)
#pragma unroll
        for (int u = 0; u < 8; ++u) {
            const int row = u * 4 + r;
            const int n = n0 + row;
            float4 v = make_float4(0.f, 0.f, 0.f, 0.f);
            if (n < N) v = *(const float4*)(x + (size_t)n * FIN + c4);
            uint2 p;
            p.x = pack2(v.x, v.y);
            p.y = pack2(v.z, v.w);
            *(uint2*)&sA[row * SAROW + c4] = p;
        }
    }
    __syncthreads();   // the ONLY barrier

    // ---- compute: pure LDS + MFMA
    f32x4 acc[2][4] = {};
#pragma unroll
    for (int kc = 0; kc < 8; ++kc) {
        bf16x8 afrag[2];
#pragma unroll
        for (int mt = 0; mt < 2; ++mt)
            afrag[mt] = *(const bf16x8*)&sA[(mt * 16 + m16) * SAROW + kc * 32 + q * 8];
#pragma unroll
        for (int ft = 0; ft < 4; ++ft) {
            union { uint4 u; bf16x8 v; } bu;
            bu.u = bfrag[ft][kc];
#pragma unroll
            for (int mt = 0; mt < 2; ++mt)
                acc[mt][ft] = __builtin_amdgcn_mfma_f32_16x16x32_bf16(afrag[mt], bu.v,
                                                                     acc[mt][ft], 0, 0, 0);
        }
    }

    // ---- store: within 16x16 tile, col = m16 (f), row = q*4 + r (n)
#pragma unroll
    for (int mt = 0; mt < 2; ++mt) {
#pragma unroll
        for (int r = 0; r < 4; ++r) {
            const int n = n0 + mt * 16 + q * 4 + r;
            if (n < N) {
#pragma unroll
                for (int ft = 0; ft < 4; ++ft)
                    outp[(size_t)n * FIN + f0 + ft * 16 + m16] = f2bf(acc[mt][ft][r] * scale);
            }
        }
    }
}

// ---------------------------------------------------------------------------
// Kernel 2: seg[n] = lower_bound(src, n)  (separate: 20K-way parallel; fusing
// into node_edge regressed in R4)
// ---------------------------------------------------------------------------
__global__ __launch_bounds__(256) void seg_kernel(const int* __restrict__ src,
                                                  int* __restrict__ seg, int N, int E) {
    const int n = blockIdx.x * 256 + threadIdx.x;
    if (n > N) return;
    int lo = 0, hi = E;
    while (lo < hi) {
        const int mid = (lo + hi) >> 1;
        if (src[mid] < n) lo = mid + 1; else hi = mid;
    }
    seg[n] = lo;
}

// ---------------------------------------------------------------------------
// Kernel 3: one wave per node; q[s] bf16 in regs, k[d] bf16 gathered.
// 4 slots x 16 sublanes; x2 unroll -> 4 outstanding uint4 loads/lane.
// ---------------------------------------------------------------------------
__global__ __launch_bounds__(256) void node_edge_kernel(const unsigned short* __restrict__ qarr,
                                                        const unsigned short* __restrict__ karr,
                                                        const int* __restrict__ dest,
                                                        const int* __restrict__ seg,
                                                        float* __restrict__ out, int N) {
    __shared__ float exlds[4][MAX_SEG];

    const int w    = threadIdx.x >> 6;
    const int lane = threadIdx.x & 63;
    const int n    = blockIdx.x * 4 + w;
    const int g    = lane >> 4;   // slot 0..3
    const int j    = lane & 15;   // sublane 0..15

    int   s0 = 0, cnt = 0;
    float inv = 0.f;

    if (n < N) {
        s0 = seg[n];
        cnt = seg[n + 1] - s0;
    }

    if (cnt > 0) {
        const uint4* __restrict__ qr = (const uint4*)(qarr + (size_t)n * FIN);
        const uint4 qa0 = qr[j];
        const uint4 qa1 = qr[16 + j];
        float4 xa, xb, xc, xd;
        xa.x = bf_lo(qa0.x); xa.y = bf_hi(qa0.x); xa.z = bf_lo(qa0.y); xa.w = bf_hi(qa0.y);
        xb.x = bf_lo(qa0.z); xb.y = bf_hi(qa0.z); xb.z = bf_lo(qa0.w); xb.w = bf_hi(qa0.w);
        xc.x = bf_lo(qa1.x); xc.y = bf_hi(qa1.x); xc.z = bf_lo(qa1.y); xc.w = bf_hi(qa1.y);
        xd.x = bf_lo(qa1.z); xd.y = bf_hi(qa1.z); xd.z = bf_lo(qa1.w); xd.w = bf_hi(qa1.w);

        float sum = 0.f;
        for (int base = 0; base < cnt; base += 64) {
            const int m = min(64, cnt - base);
            const int vd = (lane < m) ? dest[s0 + base + lane] : 0;
            const int nit = (m + 3) >> 2;
            for (int it = 0; it < nit; it += 2) {
                const int  eg0 = it * 4 + g;
                const int  eg1 = eg0 + 4;
                const bool v0  = eg0 < m;
                const bool v1  = eg1 < m;
                const int  d0  = __shfl(vd, eg0, 64);
                const int  d1  = __shfl(vd, eg1, 64);
                const uint4* __restrict__ kr0 = (const uint4*)(karr + (size_t)(v0 ? d0 : 0) * FIN);
                const uint4* __restrict__ kr1 = (const uint4*)(karr + (size_t)(v1 ? d1 : 0) * FIN);
                const uint4 q00 = kr0[j];
                const uint4 q01 = kr0[16 + j];
                const uint4 q10 = kr1[j];
                const uint4 q11 = kr1[16 + j];

                float a0 = 0.f, a1 = 0.f;
                a0 += bf_lo(q00.x) * xa.x + bf_hi(q00.x) * xa.y
                    + bf_lo(q00.y) * xa.z + bf_hi(q00.y) * xa.w
                    + bf_lo(q00.z) * xb.x + bf_hi(q00.z) * xb.y
                    + bf_lo(q00.w) * xb.z + bf_hi(q00.w) * xb.w;
                a0 += bf_lo(q01.x) * xc.x + bf_hi(q01.x) * xc.y
                    + bf_lo(q01.y) * xc.z + bf_hi(q01.y) * xc.w
                    + bf_lo(q01.z) * xd.x + bf_hi(q01.z) * xd.y
                    + bf_lo(q01.w) * xd.z + bf_hi(q01.w) * xd.w;
                a1 += bf_lo(q10.x) * xa.x + bf_hi(q10.x) * xa.y
                    + bf_lo(q10.y) * xa.z + bf_hi(q10.y) * xa.w
                    + bf_lo(q10.z) * xb.x + bf_hi(q10.z) * xb.y
                    + bf_lo(q10.w) * xb.z + bf_hi(q10.w) * xb.w;
                a1 += bf_lo(q11.x) * xc.x + bf_hi(q11.x) * xc.y
                    + bf_lo(q11.y) * xc.z + bf_hi(q11.y) * xc.w
                    + bf_lo(q11.z) * xd.x + bf_hi(q11.z) * xd.y
                    + bf_lo(q11.w) * xd.z + bf_hi(q11.w) * xd.w;

                a0 += __shfl_xor(a0, 1, 64);
                a1 += __shfl_xor(a1, 1, 64);
                a0 += __shfl_xor(a0, 2, 64);
                a1 += __shfl_xor(a1, 2, 64);
                a0 += __shfl_xor(a0, 4, 64);
                a1 += __shfl_xor(a1, 4, 64);
                a0 += __shfl_xor(a0, 8, 64);
                a1 += __shfl_xor(a1, 8, 64);

                if (v0) {
                    const float ex = __expf(a0);
                    sum += ex;
                    const int idx = base + eg0;
                    if (j == 0 && idx < MAX_SEG) exlds[w][idx] = ex;
                }
                if (v1) {
                    const float ex = __expf(a1);
                    sum += ex;
                    const int idx = base + eg1;
                    if (j == 0 && idx < MAX_SEG) exlds[w][idx] = ex;
                }
            }
        }
        sum += __shfl_xor(sum, 16, 64);
        sum += __shfl_xor(sum, 32, 64);
        inv = 1.0f / sum;
    }

    __syncthreads();

    if (cnt > 0) {
        const int lim = cnt < MAX_SEG ? cnt : MAX_SEG;
        for (int i = lane; i < lim; i += 64)
            out[s0 + i] = exlds[w][i] * inv;
    }
}

// ---------------------------------------------------------------------------
extern "C" void kernel_launch(void* const* d_in, const int* in_sizes, int n_in,
                              void* d_out, int out_size, void* d_ws, size_t ws_size,
                              hipStream_t stream) {
    const float* x  = (const float*)d_in[0];
    const int*   ei = (const int*)d_in[1];   // src = ei[0:E], dest = ei[E:2E]
    const float* W  = (const float*)d_in[2];
    float* out = (float*)d_out;

    const int N = in_sizes[0] / FIN;
    const int E = in_sizes[1] / 2;

    // workspace layout
    unsigned short* qarr = (unsigned short*)d_ws;            // N*256 bf16
    unsigned short* karr = qarr + (size_t)N * FIN;           // N*256 bf16
    unsigned short* Wb   = karr + (size_t)N * FIN;           // 512*256 bf16
    int*            seg  = (int*)(Wb + (size_t)2 * FQK * FIN); // N+1

    prep_wb_kernel<<<(2 * FQK * FIN) / (256 * 4), 256, 0, stream>>>(W, (unsigned int*)Wb);

    dim3 ggrid((N + GROWS - 1) / GROWS, 2);
    gemm_qk_kernel<<<ggrid, 256, 0, stream>>>(x, Wb, qarr, karr, N);

    seg_kernel<<<(N + 256) / 256, 256, 0, stream>>>(ei, seg, N, E);

    node_edge_kernel<<<(N + 3) / 4, 256, 0, stream>>>(qarr, karr, ei + E, seg, out, N);
}